// Round 1
// baseline (1815.964 us; speedup 1.0000x reference)
//
#include <hip/hip_runtime.h>
#include <hip/hip_bf16.h>
#include <cstdint>

#define T_TOK 32768
#define HD 512
#define ID 2048
#define NE 8

typedef __bf16 bf16x8 __attribute__((ext_vector_type(8)));
typedef float f32x4 __attribute__((ext_vector_type(4)));

__device__ __forceinline__ ushort f2bf(float f) {
  __hip_bfloat16 h = __float2bfloat16(f);
  return *reinterpret_cast<ushort*>(&h);
}

__device__ __forceinline__ void gload16(const ushort* g, ushort* l) {
  __builtin_amdgcn_global_load_lds((__attribute__((address_space(1))) void*)(void*)g,
                                   (__attribute__((address_space(3))) void*)(void*)l,
                                   16, 0, 0);
}

// ---------------- zero out + counters ----------------
__global__ void k_zero(float4* out4, int n4, int* counts) {
  if (blockIdx.x == 0 && threadIdx.x < NE) counts[threadIdx.x] = 0;
  float4 z = make_float4(0.f, 0.f, 0.f, 0.f);
  for (int i = blockIdx.x * blockDim.x + threadIdx.x; i < n4; i += gridDim.x * blockDim.x)
    out4[i] = z;
}

// ---------------- cast x -> bf16 ----------------
__global__ void k_cast_x(const float4* __restrict__ x4, ushort4* __restrict__ xb4, int n4) {
  for (int i = blockIdx.x * blockDim.x + threadIdx.x; i < n4; i += gridDim.x * blockDim.x) {
    float4 v = x4[i];
    ushort4 o;
    o.x = f2bf(v.x); o.y = f2bf(v.y); o.z = f2bf(v.z); o.w = f2bf(v.w);
    xb4[i] = o;
  }
}

// ---------------- transpose+cast weights: in [z][R][C] f32 -> out [z][C][R] bf16 ----------------
__global__ void k_transpose(const float* __restrict__ in, ushort* __restrict__ out, int R, int C) {
  __shared__ float tile[32][33];
  int z = blockIdx.z;
  const float* src = in + (size_t)z * R * C;
  ushort* dst = out + (size_t)z * R * C;
  int c0 = blockIdx.x * 32, r0 = blockIdx.y * 32;
  int tx = threadIdx.x, ty = threadIdx.y;  // (32,8)
#pragma unroll
  for (int i = 0; i < 32; i += 8)
    tile[ty + i][tx] = src[(size_t)(r0 + ty + i) * C + c0 + tx];
  __syncthreads();
#pragma unroll
  for (int i = 0; i < 32; i += 8)
    dst[(size_t)(c0 + ty + i) * R + r0 + tx] = f2bf(tile[tx][ty + i]);
}

// ---------------- gate + route: one wave per token, fp32 ----------------
__global__ __launch_bounds__(256) void k_gate(const float* __restrict__ x,
                                              const float* __restrict__ gw,
                                              const float* __restrict__ gb,
                                              int* __restrict__ rtok, float* __restrict__ rw,
                                              int* __restrict__ counts) {
  int t = blockIdx.x * 4 + (threadIdx.x >> 6);
  int lane = threadIdx.x & 63;
  const float4* xr = (const float4*)(x + (size_t)t * HD) + lane * 2;
  float4 v0 = xr[0], v1 = xr[1];
  float xv[8] = {v0.x, v0.y, v0.z, v0.w, v1.x, v1.y, v1.z, v1.w};
  float p[8] = {0, 0, 0, 0, 0, 0, 0, 0};
  const float* g = gw + lane * 64;  // gw is [512][8]; lane owns rows lane*8..lane*8+7
#pragma unroll
  for (int j = 0; j < 8; ++j) {
#pragma unroll
    for (int e = 0; e < 8; ++e) p[e] += xv[j] * g[j * 8 + e];
  }
#pragma unroll
  for (int e = 0; e < 8; ++e) {
    float s = p[e];
    for (int off = 32; off; off >>= 1) s += __shfl_xor(s, off);
    p[e] = s + gb[e];
  }
  // softmax over 8 logits (fp32, matches reference selection semantics)
  float mx = p[0];
#pragma unroll
  for (int e = 1; e < 8; ++e) mx = fmaxf(mx, p[e]);
  float Z = 0.f;
  float pr[8];
#pragma unroll
  for (int e = 0; e < 8; ++e) { pr[e] = expf(p[e] - mx); Z += pr[e]; }
  float invZ = 1.f / Z;
#pragma unroll
  for (int e = 0; e < 8; ++e) pr[e] *= invZ;
  // top-2 (strict > keeps lowest index on ties, like lax.top_k)
  float v1v = pr[0]; int i1 = 0;
#pragma unroll
  for (int e = 1; e < 8; ++e) { if (pr[e] > v1v) { v1v = pr[e]; i1 = e; } }
  float v2v = -1.f; int i2 = 0;
#pragma unroll
  for (int e = 0; e < 8; ++e) { if (e != i1 && pr[e] > v2v) { v2v = pr[e]; i2 = e; } }
  // renormalize: softmax over the two selected PROBABILITIES
  float c1 = 1.f / (1.f + expf(v2v - v1v));
  float c2 = 1.f - c1;
  if (lane == 0) {
    int a = atomicAdd(&counts[i1], 1);
    rtok[i1 * T_TOK + a] = t; rw[i1 * T_TOK + a] = c1;
    int b = atomicAdd(&counts[i2], 1);
    rtok[i2 * T_TOK + b] = t; rw[i2 * T_TOK + b] = c2;
  }
}

// ---------------- FFN GEMM1: h = relu(X[rtok] @ w1t^T + b1), bf16 out ----------------
// A: gathered x_bf16 rows [128 x 32/k-step]; B: w1t[e] rows (I-major, H-contig).
__global__ __launch_bounds__(256) void k_ffn1(const ushort* __restrict__ xb,
                                              const ushort* __restrict__ w1t,
                                              const float* __restrict__ b1,
                                              const int* __restrict__ rtok,
                                              const int* __restrict__ counts,
                                              ushort* __restrict__ h, int e, int cbase) {
  int cnt = counts[e];
  int m0 = cbase + blockIdx.x * 128;
  if (m0 >= cnt) return;
  int n0 = blockIdx.y * 128;
  __shared__ __attribute__((aligned(16))) ushort As[128 * 32];
  __shared__ __attribute__((aligned(16))) ushort Bs[128 * 32];
  int tid = threadIdx.x, lane = tid & 63, wv = tid >> 6;
  int c0id = wv * 128 + lane, c1id = c0id + 64;        // 16B-chunk ids (512 total per tile)
  int rA0 = c0id >> 2, rA1 = c1id >> 2;                // tile row (4 chunks/row)
  int kq0 = (c0id & 3) * 8, kq1 = (c1id & 3) * 8;      // element offset in row
  const int* rte = rtok + e * T_TOK;
  int tok0 = rte[min(m0 + rA0, cnt - 1)];
  int tok1 = rte[min(m0 + rA1, cnt - 1)];
  const ushort* aSrc0 = xb + (size_t)tok0 * HD + kq0;
  const ushort* aSrc1 = xb + (size_t)tok1 * HD + kq1;
  const ushort* bBase = w1t + ((size_t)e * ID + n0) * HD;
  const ushort* bSrc0 = bBase + (size_t)rA0 * HD + kq0;
  const ushort* bSrc1 = bBase + (size_t)rA1 * HD + kq1;
  ushort* aDst = As + (size_t)wv * 128 * 8;
  ushort* bDst = Bs + (size_t)wv * 128 * 8;
  f32x4 acc[4][4] = {};
  int lr = lane & 15, lk = lane >> 4;
  int wr = wv >> 1, wc = wv & 1;
  const ushort* aRd = As + ((wr * 64 + lr) * 32 + lk * 8);
  const ushort* bRd = Bs + ((wc * 64 + lr) * 32 + lk * 8);
  for (int k0 = 0; k0 < HD; k0 += 32) {
    gload16(aSrc0 + k0, aDst);
    gload16(aSrc1 + k0, aDst + 64 * 8);
    gload16(bSrc0 + k0, bDst);
    gload16(bSrc1 + k0, bDst + 64 * 8);
    __syncthreads();
    bf16x8 af[4], bfr[4];
#pragma unroll
    for (int i = 0; i < 4; ++i) {
      af[i] = *(const bf16x8*)(aRd + i * 16 * 32);
      bfr[i] = *(const bf16x8*)(bRd + i * 16 * 32);
    }
#pragma unroll
    for (int mi = 0; mi < 4; ++mi)
#pragma unroll
      for (int ni = 0; ni < 4; ++ni)
        acc[mi][ni] = __builtin_amdgcn_mfma_f32_16x16x32_bf16(af[mi], bfr[ni], acc[mi][ni], 0, 0, 0);
    __syncthreads();
  }
  int hrow0 = blockIdx.x * 128;
#pragma unroll
  for (int ni = 0; ni < 4; ++ni) {
    int ng = n0 + wc * 64 + ni * 16 + lr;
    float bv = b1[e * ID + ng];
#pragma unroll
    for (int mi = 0; mi < 4; ++mi) {
      int rbase = hrow0 + wr * 64 + mi * 16 + lk * 4;
#pragma unroll
      for (int r = 0; r < 4; ++r) {
        float v = acc[mi][ni][r] + bv;
        v = fmaxf(v, 0.f);
        h[(size_t)(rbase + r) * ID + ng] = f2bf(v);
      }
    }
  }
}

// ---------------- FFN GEMM2: out[tok] += coef * (h @ w2t^T + b2) ----------------
__global__ __launch_bounds__(256) void k_ffn2(const ushort* __restrict__ h,
                                              const ushort* __restrict__ w2t,
                                              const float* __restrict__ b2,
                                              const int* __restrict__ rtok,
                                              const float* __restrict__ rw,
                                              const int* __restrict__ counts,
                                              float* __restrict__ out, int e, int cbase) {
  int cnt = counts[e];
  int m0 = cbase + blockIdx.x * 128;
  if (m0 >= cnt) return;
  int n0 = blockIdx.y * 128;
  __shared__ __attribute__((aligned(16))) ushort As[128 * 32];
  __shared__ __attribute__((aligned(16))) ushort Bs[128 * 32];
  __shared__ int stok[128];
  __shared__ float scoef[128];
  int tid = threadIdx.x, lane = tid & 63, wv = tid >> 6;
  if (tid < 128) {
    int idx = min(m0 + tid, cnt - 1);
    stok[tid] = rtok[e * T_TOK + idx];
    scoef[tid] = rw[e * T_TOK + idx];
  }
  int c0id = wv * 128 + lane, c1id = c0id + 64;
  int rA0 = c0id >> 2, rA1 = c1id >> 2;
  int kq0 = (c0id & 3) * 8, kq1 = (c1id & 3) * 8;
  int hrow0 = blockIdx.x * 128;
  const ushort* aSrc0 = h + (size_t)(hrow0 + rA0) * ID + kq0;
  const ushort* aSrc1 = h + (size_t)(hrow0 + rA1) * ID + kq1;
  const ushort* bBase = w2t + ((size_t)e * HD + n0) * ID;
  const ushort* bSrc0 = bBase + (size_t)rA0 * ID + kq0;
  const ushort* bSrc1 = bBase + (size_t)rA1 * ID + kq1;
  ushort* aDst = As + (size_t)wv * 128 * 8;
  ushort* bDst = Bs + (size_t)wv * 128 * 8;
  f32x4 acc[4][4] = {};
  int lr = lane & 15, lk = lane >> 4;
  int wr = wv >> 1, wc = wv & 1;
  const ushort* aRd = As + ((wr * 64 + lr) * 32 + lk * 8);
  const ushort* bRd = Bs + ((wc * 64 + lr) * 32 + lk * 8);
  for (int k0 = 0; k0 < ID; k0 += 32) {
    gload16(aSrc0 + k0, aDst);
    gload16(aSrc1 + k0, aDst + 64 * 8);
    gload16(bSrc0 + k0, bDst);
    gload16(bSrc1 + k0, bDst + 64 * 8);
    __syncthreads();
    bf16x8 af[4], bfr[4];
#pragma unroll
    for (int i = 0; i < 4; ++i) {
      af[i] = *(const bf16x8*)(aRd + i * 16 * 32);
      bfr[i] = *(const bf16x8*)(bRd + i * 16 * 32);
    }
#pragma unroll
    for (int mi = 0; mi < 4; ++mi)
#pragma unroll
      for (int ni = 0; ni < 4; ++ni)
        acc[mi][ni] = __builtin_amdgcn_mfma_f32_16x16x32_bf16(af[mi], bfr[ni], acc[mi][ni], 0, 0, 0);
    __syncthreads();
  }
#pragma unroll
  for (int ni = 0; ni < 4; ++ni) {
    int ng = n0 + wc * 64 + ni * 16 + lr;  // < 512
    float b2v = b2[e * HD + ng];
#pragma unroll
    for (int mi = 0; mi < 4; ++mi) {
      int rloc = wr * 64 + mi * 16 + lk * 4;
#pragma unroll
      for (int r = 0; r < 4; ++r) {
        int m_l = rloc + r;
        if (m0 + m_l < cnt) {
          float v = (acc[mi][ni][r] + b2v) * scoef[m_l];
          size_t oi = (size_t)stok[m_l] * HD + ng;
          out[oi] += v;  // stream-serialized across experts; unique (tok,ng) within a kernel
        }
      }
    }
  }
}

// ---------------- host ----------------
extern "C" void kernel_launch(void* const* d_in, const int* in_sizes, int n_in,
                              void* d_out, int out_size, void* d_ws, size_t ws_size,
                              hipStream_t stream) {
  const float* x  = (const float*)d_in[0];
  const float* gw = (const float*)d_in[1];
  const float* gb = (const float*)d_in[2];
  const float* w1 = (const float*)d_in[3];
  const float* b1 = (const float*)d_in[4];
  const float* w2 = (const float*)d_in[5];
  const float* b2 = (const float*)d_in[6];
  float* out = (float*)d_out;

  char* p = (char*)d_ws;
  ushort* xb   = (ushort*)p; p += (size_t)T_TOK * HD * 2;   // 33.5 MB
  ushort* w1t  = (ushort*)p; p += (size_t)NE * ID * HD * 2; // 16.8 MB
  ushort* w2t  = (ushort*)p; p += (size_t)NE * HD * ID * 2; // 16.8 MB
  int*    rtok = (int*)p;    p += (size_t)NE * T_TOK * 4;   // 1 MB
  float*  rw   = (float*)p;  p += (size_t)NE * T_TOK * 4;   // 1 MB
  int*  counts = (int*)p;    p += 128;
  ushort* hbuf = (ushort*)p;
  size_t fixed = (size_t)(p - (char*)d_ws);
  size_t avail = ws_size > fixed ? ws_size - fixed : 0;

  int MC;  // h-buffer token capacity per expert-chunk (ws_size-dependent, constant per session)
  if ((size_t)32768 * ID * 2 <= avail)      MC = 32768;
  else if ((size_t)16384 * ID * 2 <= avail) MC = 16384;
  else if ((size_t)8192 * ID * 2 <= avail)  MC = 8192;
  else                                      MC = 4096;
  int nchunk = (T_TOK + MC - 1) / MC;

  k_zero<<<2048, 256, 0, stream>>>((float4*)out, T_TOK * HD / 4, counts);
  k_cast_x<<<2048, 256, 0, stream>>>((const float4*)x, (ushort4*)xb, T_TOK * HD / 4);
  // w1: [E][512][2048] -> w1t [E][2048][512]
  k_transpose<<<dim3(ID / 32, HD / 32, NE), dim3(32, 8), 0, stream>>>(w1, w1t, HD, ID);
  // w2: [E][2048][512] -> w2t [E][512][2048]
  k_transpose<<<dim3(HD / 32, ID / 32, NE), dim3(32, 8), 0, stream>>>(w2, w2t, ID, HD);
  k_gate<<<T_TOK / 4, 256, 0, stream>>>(x, gw, gb, rtok, rw, counts);

  for (int e = 0; e < NE; ++e) {
    for (int c = 0; c < nchunk; ++c) {
      k_ffn1<<<dim3(MC / 128, ID / 128), 256, 0, stream>>>(xb, w1t, b1, rtok, counts, hbuf, e, c * MC);
      k_ffn2<<<dim3(MC / 128, HD / 128), 256, 0, stream>>>(hbuf, w2t, b2, rtok, rw, counts, out, e, c * MC);
    }
  }
}

// Round 3
// 1119.529 us; speedup vs baseline: 1.6221x; 1.6221x over previous
//
#include <hip/hip_runtime.h>
#include <hip/hip_bf16.h>
#include <cstdint>

#define T_TOK 32768
#define HD 512
#define ID 2048
#define NE 8

typedef __bf16 bf16x8 __attribute__((ext_vector_type(8)));
typedef float f32x4 __attribute__((ext_vector_type(4)));

__device__ __forceinline__ ushort f2bf(float f) {
  __hip_bfloat16 h = __float2bfloat16(f);
  return *reinterpret_cast<ushort*>(&h);
}

__device__ __forceinline__ void gload16(const ushort* g, ushort* l) {
  __builtin_amdgcn_global_load_lds((__attribute__((address_space(1))) void*)(void*)g,
                                   (__attribute__((address_space(3))) void*)(void*)l,
                                   16, 0, 0);
}

// ---------------- zero out + counters ----------------
__global__ void k_zero(float4* out4, int n4, int* counts) {
  if (blockIdx.x == 0 && threadIdx.x < NE) counts[threadIdx.x] = 0;
  float4 z = make_float4(0.f, 0.f, 0.f, 0.f);
  for (int i = blockIdx.x * blockDim.x + threadIdx.x; i < n4; i += gridDim.x * blockDim.x)
    out4[i] = z;
}

// ---------------- transpose+cast weights: in [z][R][C] f32 -> out [z][C][R] bf16 ----------------
__global__ void k_transpose(const float* __restrict__ in, ushort* __restrict__ out, int R, int C) {
  __shared__ float tile[32][33];
  int z = blockIdx.z;
  const float* src = in + (size_t)z * R * C;
  ushort* dst = out + (size_t)z * R * C;
  int c0 = blockIdx.x * 32, r0 = blockIdx.y * 32;
  int tx = threadIdx.x, ty = threadIdx.y;  // (32,8)
#pragma unroll
  for (int i = 0; i < 32; i += 8)
    tile[ty + i][tx] = src[(size_t)(r0 + ty + i) * C + c0 + tx];
  __syncthreads();
#pragma unroll
  for (int i = 0; i < 32; i += 8)
    dst[(size_t)(c0 + ty + i) * R + r0 + tx] = f2bf(tile[tx][ty + i]);
}

// ---------------- fused cast x->bf16 + gate top-2 (NO atomics) ----------------
// One wave per token. Writes per-token expert pair + renormalized coefs.
__global__ __launch_bounds__(256) void k_cast_gate(const float* __restrict__ x,
                                                   const float* __restrict__ gw,
                                                   const float* __restrict__ gb,
                                                   ushort* __restrict__ xb,
                                                   uchar2* __restrict__ tope,
                                                   float2* __restrict__ tw) {
  int t = blockIdx.x * 4 + (threadIdx.x >> 6);
  int lane = threadIdx.x & 63;
  const float4* xr = (const float4*)(x + (size_t)t * HD);
  float4 v0 = xr[lane];        // h = lane*4 .. lane*4+3
  float4 v1 = xr[lane + 64];   // h = 256 + lane*4 .. +3
  // cast + store bf16 (coalesced)
  ushort4 o0, o1;
  o0.x = f2bf(v0.x); o0.y = f2bf(v0.y); o0.z = f2bf(v0.z); o0.w = f2bf(v0.w);
  o1.x = f2bf(v1.x); o1.y = f2bf(v1.y); o1.z = f2bf(v1.z); o1.w = f2bf(v1.w);
  ushort4* xw = (ushort4*)(xb + (size_t)t * HD);
  xw[lane] = o0;
  xw[lane + 64] = o1;
  // gate logits: p[e] = sum_h x[h]*gw[h][e]
  float xv[8] = {v0.x, v0.y, v0.z, v0.w, v1.x, v1.y, v1.z, v1.w};
  float p[8] = {0, 0, 0, 0, 0, 0, 0, 0};
  const float* g0 = gw + (size_t)lane * 4 * 8;           // rows lane*4..+3
  const float* g1 = gw + (size_t)(256 + lane * 4) * 8;   // rows 256+lane*4..+3
#pragma unroll
  for (int j = 0; j < 4; ++j)
#pragma unroll
    for (int e = 0; e < 8; ++e) p[e] += xv[j] * g0[j * 8 + e];
#pragma unroll
  for (int j = 0; j < 4; ++j)
#pragma unroll
    for (int e = 0; e < 8; ++e) p[e] += xv[4 + j] * g1[j * 8 + e];
#pragma unroll
  for (int e = 0; e < 8; ++e) {
    float s = p[e];
    for (int off = 32; off; off >>= 1) s += __shfl_xor(s, off);
    p[e] = s + gb[e];
  }
  // softmax over 8 logits (fp32; selection semantics match lax.top_k)
  float mx = p[0];
#pragma unroll
  for (int e = 1; e < 8; ++e) mx = fmaxf(mx, p[e]);
  float Z = 0.f;
  float pr[8];
#pragma unroll
  for (int e = 0; e < 8; ++e) { pr[e] = expf(p[e] - mx); Z += pr[e]; }
  float invZ = 1.f / Z;
#pragma unroll
  for (int e = 0; e < 8; ++e) pr[e] *= invZ;
  // top-2 (strict > keeps lowest index on ties)
  float v1v = pr[0]; int i1 = 0;
#pragma unroll
  for (int e = 1; e < 8; ++e) { if (pr[e] > v1v) { v1v = pr[e]; i1 = e; } }
  float v2v = -1.f; int i2 = 0;
#pragma unroll
  for (int e = 0; e < 8; ++e) { if (e != i1 && pr[e] > v2v) { v2v = pr[e]; i2 = e; } }
  float c1 = 1.f / (1.f + expf(v2v - v1v));  // softmax over selected probs
  float c2 = 1.f - c1;
  if (lane == 0) {
    tope[t] = make_uchar2((unsigned char)i1, (unsigned char)i2);
    tw[t] = make_float2(c1, c2);
  }
}

// ---------------- route: wave-aggregated compaction (1 atomic per wave per expert) ----------------
__global__ __launch_bounds__(256) void k_route(const uchar2* __restrict__ tope,
                                               const float2* __restrict__ tw,
                                               int* __restrict__ rtok, float* __restrict__ rw,
                                               int* __restrict__ counts) {
  int t = blockIdx.x * 256 + threadIdx.x;
  int lane = threadIdx.x & 63;
  uchar2 ei = tope[t];
  float2 c = tw[t];
  unsigned long long below = (1ull << lane) - 1ull;
#pragma unroll
  for (int e = 0; e < NE; ++e) {
    bool sel = (ei.x == e) || (ei.y == e);  // i1 != i2, at most one slot matches
    unsigned long long mask = __ballot(sel);
    if (mask == 0ull) continue;
    int cnt = __popcll(mask);
    int base = 0;
    if (lane == 0) base = atomicAdd(&counts[e], cnt);
    base = __shfl(base, 0);
    if (sel) {
      int pos = base + __popcll(mask & below);
      rtok[e * T_TOK + pos] = t;
      rw[e * T_TOK + pos] = (ei.x == e) ? c.x : c.y;
    }
  }
}

// ---------------- FFN GEMM1: h = relu(X[rtok] @ w1t^T + b1), bf16 out ----------------
__global__ __launch_bounds__(256) void k_ffn1(const ushort* __restrict__ xb,
                                              const ushort* __restrict__ w1t,
                                              const float* __restrict__ b1,
                                              const int* __restrict__ rtok,
                                              const int* __restrict__ counts,
                                              ushort* __restrict__ h, int e, int cbase) {
  int cnt = counts[e];
  int m0 = cbase + blockIdx.x * 128;
  if (m0 >= cnt) return;
  int n0 = blockIdx.y * 128;
  __shared__ __attribute__((aligned(16))) ushort As[128 * 32];
  __shared__ __attribute__((aligned(16))) ushort Bs[128 * 32];
  int tid = threadIdx.x, lane = tid & 63, wv = tid >> 6;
  int c0id = wv * 128 + lane, c1id = c0id + 64;        // 16B-chunk ids (512 total per tile)
  int rA0 = c0id >> 2, rA1 = c1id >> 2;                // tile row (4 chunks/row)
  int kq0 = (c0id & 3) * 8, kq1 = (c1id & 3) * 8;      // element offset in row
  const int* rte = rtok + e * T_TOK;
  int tok0 = rte[min(m0 + rA0, cnt - 1)];
  int tok1 = rte[min(m0 + rA1, cnt - 1)];
  const ushort* aSrc0 = xb + (size_t)tok0 * HD + kq0;
  const ushort* aSrc1 = xb + (size_t)tok1 * HD + kq1;
  const ushort* bBase = w1t + ((size_t)e * ID + n0) * HD;
  const ushort* bSrc0 = bBase + (size_t)rA0 * HD + kq0;
  const ushort* bSrc1 = bBase + (size_t)rA1 * HD + kq1;
  ushort* aDst = As + (size_t)wv * 128 * 8;
  ushort* bDst = Bs + (size_t)wv * 128 * 8;
  f32x4 acc[4][4] = {};
  int lr = lane & 15, lk = lane >> 4;
  int wr = wv >> 1, wc = wv & 1;
  const ushort* aRd = As + ((wr * 64 + lr) * 32 + lk * 8);
  const ushort* bRd = Bs + ((wc * 64 + lr) * 32 + lk * 8);
  for (int k0 = 0; k0 < HD; k0 += 32) {
    gload16(aSrc0 + k0, aDst);
    gload16(aSrc1 + k0, aDst + 64 * 8);
    gload16(bSrc0 + k0, bDst);
    gload16(bSrc1 + k0, bDst + 64 * 8);
    __syncthreads();
    bf16x8 af[4], bfr[4];
#pragma unroll
    for (int i = 0; i < 4; ++i) {
      af[i] = *(const bf16x8*)(aRd + i * 16 * 32);
      bfr[i] = *(const bf16x8*)(bRd + i * 16 * 32);
    }
#pragma unroll
    for (int mi = 0; mi < 4; ++mi)
#pragma unroll
      for (int ni = 0; ni < 4; ++ni)
        acc[mi][ni] = __builtin_amdgcn_mfma_f32_16x16x32_bf16(af[mi], bfr[ni], acc[mi][ni], 0, 0, 0);
    __syncthreads();
  }
  int hrow0 = blockIdx.x * 128;
#pragma unroll
  for (int ni = 0; ni < 4; ++ni) {
    int ng = n0 + wc * 64 + ni * 16 + lr;
    float bv = b1[e * ID + ng];
#pragma unroll
    for (int mi = 0; mi < 4; ++mi) {
      int rbase = hrow0 + wr * 64 + mi * 16 + lk * 4;
#pragma unroll
      for (int r = 0; r < 4; ++r) {
        float v = acc[mi][ni][r] + bv;
        v = fmaxf(v, 0.f);
        h[(size_t)(rbase + r) * ID + ng] = f2bf(v);
      }
    }
  }
}

// ---------------- FFN GEMM2: out[tok] += coef * (h @ w2t^T + b2) ----------------
__global__ __launch_bounds__(256) void k_ffn2(const ushort* __restrict__ h,
                                              const ushort* __restrict__ w2t,
                                              const float* __restrict__ b2,
                                              const int* __restrict__ rtok,
                                              const float* __restrict__ rw,
                                              const int* __restrict__ counts,
                                              float* __restrict__ out, int e, int cbase) {
  int cnt = counts[e];
  int m0 = cbase + blockIdx.x * 128;
  if (m0 >= cnt) return;
  int n0 = blockIdx.y * 128;
  __shared__ __attribute__((aligned(16))) ushort As[128 * 32];
  __shared__ __attribute__((aligned(16))) ushort Bs[128 * 32];
  __shared__ int stok[128];
  __shared__ float scoef[128];
  int tid = threadIdx.x, lane = tid & 63, wv = tid >> 6;
  if (tid < 128) {
    int idx = min(m0 + tid, cnt - 1);
    stok[tid] = rtok[e * T_TOK + idx];
    scoef[tid] = rw[e * T_TOK + idx];
  }
  int c0id = wv * 128 + lane, c1id = c0id + 64;
  int rA0 = c0id >> 2, rA1 = c1id >> 2;
  int kq0 = (c0id & 3) * 8, kq1 = (c1id & 3) * 8;
  int hrow0 = blockIdx.x * 128;
  const ushort* aSrc0 = h + (size_t)(hrow0 + rA0) * ID + kq0;
  const ushort* aSrc1 = h + (size_t)(hrow0 + rA1) * ID + kq1;
  const ushort* bBase = w2t + ((size_t)e * HD + n0) * ID;
  const ushort* bSrc0 = bBase + (size_t)rA0 * ID + kq0;
  const ushort* bSrc1 = bBase + (size_t)rA1 * ID + kq1;
  ushort* aDst = As + (size_t)wv * 128 * 8;
  ushort* bDst = Bs + (size_t)wv * 128 * 8;
  f32x4 acc[4][4] = {};
  int lr = lane & 15, lk = lane >> 4;
  int wr = wv >> 1, wc = wv & 1;
  const ushort* aRd = As + ((wr * 64 + lr) * 32 + lk * 8);
  const ushort* bRd = Bs + ((wc * 64 + lr) * 32 + lk * 8);
  for (int k0 = 0; k0 < ID; k0 += 32) {
    gload16(aSrc0 + k0, aDst);
    gload16(aSrc1 + k0, aDst + 64 * 8);
    gload16(bSrc0 + k0, bDst);
    gload16(bSrc1 + k0, bDst + 64 * 8);
    __syncthreads();
    bf16x8 af[4], bfr[4];
#pragma unroll
    for (int i = 0; i < 4; ++i) {
      af[i] = *(const bf16x8*)(aRd + i * 16 * 32);
      bfr[i] = *(const bf16x8*)(bRd + i * 16 * 32);
    }
#pragma unroll
    for (int mi = 0; mi < 4; ++mi)
#pragma unroll
      for (int ni = 0; ni < 4; ++ni)
        acc[mi][ni] = __builtin_amdgcn_mfma_f32_16x16x32_bf16(af[mi], bfr[ni], acc[mi][ni], 0, 0, 0);
    __syncthreads();
  }
#pragma unroll
  for (int ni = 0; ni < 4; ++ni) {
    int ng = n0 + wc * 64 + ni * 16 + lr;  // < 512
    float b2v = b2[e * HD + ng];
#pragma unroll
    for (int mi = 0; mi < 4; ++mi) {
      int rloc = wr * 64 + mi * 16 + lk * 4;
#pragma unroll
      for (int r = 0; r < 4; ++r) {
        int m_l = rloc + r;
        if (m0 + m_l < cnt) {
          float v = (acc[mi][ni][r] + b2v) * scoef[m_l];
          size_t oi = (size_t)stok[m_l] * HD + ng;
          out[oi] += v;  // stream-serialized across experts; unique (tok,ng) within a kernel
        }
      }
    }
  }
}

// ---------------- host ----------------
extern "C" void kernel_launch(void* const* d_in, const int* in_sizes, int n_in,
                              void* d_out, int out_size, void* d_ws, size_t ws_size,
                              hipStream_t stream) {
  const float* x  = (const float*)d_in[0];
  const float* gw = (const float*)d_in[1];
  const float* gb = (const float*)d_in[2];
  const float* w1 = (const float*)d_in[3];
  const float* b1 = (const float*)d_in[4];
  const float* w2 = (const float*)d_in[5];
  const float* b2 = (const float*)d_in[6];
  float* out = (float*)d_out;

  char* p = (char*)d_ws;
  ushort* xb   = (ushort*)p; p += (size_t)T_TOK * HD * 2;   // 33.5 MB
  ushort* w1t  = (ushort*)p; p += (size_t)NE * ID * HD * 2; // 16.8 MB
  ushort* w2t  = (ushort*)p; p += (size_t)NE * HD * ID * 2; // 16.8 MB
  int*    rtok = (int*)p;    p += (size_t)NE * T_TOK * 4;   // 1 MB
  float*  rw   = (float*)p;  p += (size_t)NE * T_TOK * 4;   // 1 MB
  uchar2* tope = (uchar2*)p; p += (size_t)T_TOK * 2;
  float2* tw   = (float2*)p; p += (size_t)T_TOK * 8;
  int*  counts = (int*)p;    p += 128;
  ushort* hbuf = (ushort*)p;
  size_t fixed = (size_t)(p - (char*)d_ws);
  size_t avail = ws_size > fixed ? ws_size - fixed : 0;

  int MC;  // h-buffer token capacity per expert-chunk (ws_size-dependent, constant per session)
  if ((size_t)32768 * ID * 2 <= avail)      MC = 32768;
  else if ((size_t)16384 * ID * 2 <= avail) MC = 16384;
  else if ((size_t)8192 * ID * 2 <= avail)  MC = 8192;
  else                                      MC = 4096;
  int nchunk = (T_TOK + MC - 1) / MC;

  k_zero<<<2048, 256, 0, stream>>>((float4*)out, T_TOK * HD / 4, counts);
  k_cast_gate<<<T_TOK / 4, 256, 0, stream>>>(x, gw, gb, xb, tope, tw);
  k_route<<<T_TOK / 256, 256, 0, stream>>>(tope, tw, rtok, rw, counts);
  // w1: [E][512][2048] -> w1t [E][2048][512]
  k_transpose<<<dim3(ID / 32, HD / 32, NE), dim3(32, 8), 0, stream>>>(w1, w1t, HD, ID);
  // w2: [E][2048][512] -> w2t [E][512][2048]
  k_transpose<<<dim3(HD / 32, ID / 32, NE), dim3(32, 8), 0, stream>>>(w2, w2t, ID, HD);

  for (int e = 0; e < NE; ++e) {
    for (int c = 0; c < nchunk; ++c) {
      k_ffn1<<<dim3(MC / 128, ID / 128), 256, 0, stream>>>(xb, w1t, b1, rtok, counts, hbuf, e, c * MC);
      k_ffn2<<<dim3(MC / 128, HD / 128), 256, 0, stream>>>(hbuf, w2t, b2, rtok, rw, counts, out, e, c * MC);
    }
  }
}

// Round 5
// 947.946 us; speedup vs baseline: 1.9157x; 1.1810x over previous
//
#include <hip/hip_runtime.h>
#include <hip/hip_bf16.h>
#include <cstdint>

#define T_TOK 32768
#define HD 512
#define ID 2048
#define NE 8

typedef __bf16 bf16x8 __attribute__((ext_vector_type(8)));
typedef float f32x4 __attribute__((ext_vector_type(4)));

__device__ __forceinline__ ushort f2bf(float f) {
  __hip_bfloat16 h = __float2bfloat16(f);
  return *reinterpret_cast<ushort*>(&h);
}

__device__ __forceinline__ void gload16(const ushort* g, ushort* l) {
  __builtin_amdgcn_global_load_lds((__attribute__((address_space(1))) void*)(void*)g,
                                   (__attribute__((address_space(3))) void*)(void*)l,
                                   16, 0, 0);
}

// ---------------- zero out + routing counters ----------------
__global__ void k_zero(float4* out4, int n4, int* counts) {
  if (blockIdx.x == 0 && threadIdx.x < NE) counts[threadIdx.x] = 0;
  float4 z = make_float4(0.f, 0.f, 0.f, 0.f);
  for (int i = blockIdx.x * blockDim.x + threadIdx.x; i < n4; i += gridDim.x * blockDim.x)
    out4[i] = z;
}

// ---------------- transpose+cast weights: in [z][R][C] f32 -> out [z][C][R] bf16 ----------------
__global__ void k_transpose(const float* __restrict__ in, ushort* __restrict__ out, int R, int C) {
  __shared__ float tile[32][33];
  int z = blockIdx.z;
  const float* src = in + (size_t)z * R * C;
  ushort* dst = out + (size_t)z * R * C;
  int c0 = blockIdx.x * 32, r0 = blockIdx.y * 32;
  int tx = threadIdx.x, ty = threadIdx.y;  // (32,8)
#pragma unroll
  for (int i = 0; i < 32; i += 8)
    tile[ty + i][tx] = src[(size_t)(r0 + ty + i) * C + c0 + tx];
  __syncthreads();
#pragma unroll
  for (int i = 0; i < 32; i += 8)
    dst[(size_t)(c0 + ty + i) * R + r0 + tx] = f2bf(tile[tx][ty + i]);
}

// ---------------- fused cast x->bf16 + gate top-2 (NO atomics) ----------------
__global__ __launch_bounds__(256) void k_cast_gate(const float* __restrict__ x,
                                                   const float* __restrict__ gw,
                                                   const float* __restrict__ gb,
                                                   ushort* __restrict__ xb,
                                                   uchar2* __restrict__ tope,
                                                   float2* __restrict__ tw) {
  int t = blockIdx.x * 4 + (threadIdx.x >> 6);
  int lane = threadIdx.x & 63;
  const float4* xr = (const float4*)(x + (size_t)t * HD);
  float4 v0 = xr[lane];        // h = lane*4 .. lane*4+3
  float4 v1 = xr[lane + 64];   // h = 256 + lane*4 .. +3
  ushort4 o0, o1;
  o0.x = f2bf(v0.x); o0.y = f2bf(v0.y); o0.z = f2bf(v0.z); o0.w = f2bf(v0.w);
  o1.x = f2bf(v1.x); o1.y = f2bf(v1.y); o1.z = f2bf(v1.z); o1.w = f2bf(v1.w);
  ushort4* xw = (ushort4*)(xb + (size_t)t * HD);
  xw[lane] = o0;
  xw[lane + 64] = o1;
  float xv[8] = {v0.x, v0.y, v0.z, v0.w, v1.x, v1.y, v1.z, v1.w};
  float p[8] = {0, 0, 0, 0, 0, 0, 0, 0};
  const float* g0 = gw + (size_t)lane * 4 * 8;
  const float* g1 = gw + (size_t)(256 + lane * 4) * 8;
#pragma unroll
  for (int j = 0; j < 4; ++j)
#pragma unroll
    for (int e = 0; e < 8; ++e) p[e] += xv[j] * g0[j * 8 + e];
#pragma unroll
  for (int j = 0; j < 4; ++j)
#pragma unroll
    for (int e = 0; e < 8; ++e) p[e] += xv[4 + j] * g1[j * 8 + e];
#pragma unroll
  for (int e = 0; e < 8; ++e) {
    float s = p[e];
    for (int off = 32; off; off >>= 1) s += __shfl_xor(s, off);
    p[e] = s + gb[e];
  }
  float mx = p[0];
#pragma unroll
  for (int e = 1; e < 8; ++e) mx = fmaxf(mx, p[e]);
  float Z = 0.f;
  float pr[8];
#pragma unroll
  for (int e = 0; e < 8; ++e) { pr[e] = expf(p[e] - mx); Z += pr[e]; }
  float invZ = 1.f / Z;
#pragma unroll
  for (int e = 0; e < 8; ++e) pr[e] *= invZ;
  float v1v = pr[0]; int i1 = 0;
#pragma unroll
  for (int e = 1; e < 8; ++e) { if (pr[e] > v1v) { v1v = pr[e]; i1 = e; } }
  float v2v = -1.f; int i2 = 0;
#pragma unroll
  for (int e = 0; e < 8; ++e) { if (e != i1 && pr[e] > v2v) { v2v = pr[e]; i2 = e; } }
  float c1 = 1.f / (1.f + expf(v2v - v1v));  // softmax over selected probs
  float c2 = 1.f - c1;
  if (lane == 0) {
    tope[t] = make_uchar2((unsigned char)i1, (unsigned char)i2);
    tw[t] = make_float2(c1, c2);
  }
}

// ---------------- route: wave-aggregated compaction (1 atomic per wave per expert) ----------------
__global__ __launch_bounds__(256) void k_route(const uchar2* __restrict__ tope,
                                               const float2* __restrict__ tw,
                                               int* __restrict__ rtok, float* __restrict__ rw,
                                               int* __restrict__ counts) {
  int t = blockIdx.x * 256 + threadIdx.x;
  int lane = threadIdx.x & 63;
  uchar2 ei = tope[t];
  float2 c = tw[t];
  unsigned long long below = (1ull << lane) - 1ull;
#pragma unroll
  for (int e = 0; e < NE; ++e) {
    bool sel = (ei.x == e) || (ei.y == e);  // i1 != i2, at most one slot matches
    unsigned long long mask = __ballot(sel);
    if (mask == 0ull) continue;
    int cnt = __popcll(mask);
    int base = 0;
    if (lane == 0) base = atomicAdd(&counts[e], cnt);
    base = __shfl(base, 0);
    if (sel) {
      int pos = base + __popcll(mask & below);
      rtok[e * T_TOK + pos] = t;
      rw[e * T_TOK + pos] = (ei.x == e) ? c.x : c.y;
    }
  }
}

// ---------------- FFN GEMM1 (all experts): h = relu(X[rtok] @ w1t^T + b1), bf16 ----------------
__global__ __launch_bounds__(256) void k_ffn1(const ushort* __restrict__ xb,
                                              const ushort* __restrict__ w1t,
                                              const float* __restrict__ b1,
                                              const int* __restrict__ rtok,
                                              const int* __restrict__ counts,
                                              ushort* __restrict__ h, int cbase, int MC) {
  int e = blockIdx.z;
  int cnt = counts[e];
  int m0 = cbase + blockIdx.x * 128;
  if (m0 >= cnt) return;
  int n0 = blockIdx.y * 128;
  __shared__ __attribute__((aligned(16))) ushort As[128 * 32];
  __shared__ __attribute__((aligned(16))) ushort Bs[128 * 32];
  int tid = threadIdx.x, lane = tid & 63, wv = tid >> 6;
  int c0id = wv * 128 + lane, c1id = c0id + 64;
  int rA0 = c0id >> 2, rA1 = c1id >> 2;
  int kq0 = (c0id & 3) * 8, kq1 = (c1id & 3) * 8;
  const int* rte = rtok + e * T_TOK;
  int tok0 = rte[min(m0 + rA0, cnt - 1)];
  int tok1 = rte[min(m0 + rA1, cnt - 1)];
  const ushort* aSrc0 = xb + (size_t)tok0 * HD + kq0;
  const ushort* aSrc1 = xb + (size_t)tok1 * HD + kq1;
  const ushort* bBase = w1t + ((size_t)e * ID + n0) * HD;
  const ushort* bSrc0 = bBase + (size_t)rA0 * HD + kq0;
  const ushort* bSrc1 = bBase + (size_t)rA1 * HD + kq1;
  ushort* aDst = As + (size_t)wv * 128 * 8;
  ushort* bDst = Bs + (size_t)wv * 128 * 8;
  f32x4 acc[4][4] = {};
  int lr = lane & 15, lk = lane >> 4;
  int wr = wv >> 1, wc = wv & 1;
  const ushort* aRd = As + ((wr * 64 + lr) * 32 + lk * 8);
  const ushort* bRd = Bs + ((wc * 64 + lr) * 32 + lk * 8);
  for (int k0 = 0; k0 < HD; k0 += 32) {
    gload16(aSrc0 + k0, aDst);
    gload16(aSrc1 + k0, aDst + 64 * 8);
    gload16(bSrc0 + k0, bDst);
    gload16(bSrc1 + k0, bDst + 64 * 8);
    __syncthreads();
    bf16x8 af[4], bfr[4];
#pragma unroll
    for (int i = 0; i < 4; ++i) {
      af[i] = *(const bf16x8*)(aRd + i * 16 * 32);
      bfr[i] = *(const bf16x8*)(bRd + i * 16 * 32);
    }
#pragma unroll
    for (int mi = 0; mi < 4; ++mi)
#pragma unroll
      for (int ni = 0; ni < 4; ++ni)
        acc[mi][ni] = __builtin_amdgcn_mfma_f32_16x16x32_bf16(af[mi], bfr[ni], acc[mi][ni], 0, 0, 0);
    __syncthreads();
  }
  // h slot: [e][chunk-local row][ID]
  ushort* he = h + (size_t)e * MC * ID;
  int hrow0 = blockIdx.x * 128;
#pragma unroll
  for (int ni = 0; ni < 4; ++ni) {
    int ng = n0 + wc * 64 + ni * 16 + lr;
    float bv = b1[e * ID + ng];
#pragma unroll
    for (int mi = 0; mi < 4; ++mi) {
      int rbase = hrow0 + wr * 64 + mi * 16 + lk * 4;
#pragma unroll
      for (int r = 0; r < 4; ++r) {
        float v = acc[mi][ni][r] + bv;
        v = fmaxf(v, 0.f);
        he[(size_t)(rbase + r) * ID + ng] = f2bf(v);
      }
    }
  }
}

// ---------------- FFN GEMM2 (all experts): out[tok] += coef*(h @ w2t^T + b2), atomic ----
// Native f32 global atomic add resolves the only hazard (same token routed to two
// experts processed concurrently in this dispatch). Order-invariant (2 commuting adds).
__global__ __launch_bounds__(256) void k_ffn2(const ushort* __restrict__ h,
                                              const ushort* __restrict__ w2t,
                                              const float* __restrict__ b2,
                                              const int* __restrict__ rtok,
                                              const float* __restrict__ rw,
                                              const int* __restrict__ counts,
                                              float* __restrict__ out, int cbase, int MC) {
  int e = blockIdx.z;
  int cnt = counts[e];
  int m0 = cbase + blockIdx.x * 128;
  if (m0 >= cnt) return;
  int n0 = blockIdx.y * 128;
  __shared__ __attribute__((aligned(16))) ushort As[128 * 32];
  __shared__ __attribute__((aligned(16))) ushort Bs[128 * 32];
  __shared__ int stok[128];
  __shared__ float scoef[128];
  int tid = threadIdx.x, lane = tid & 63, wv = tid >> 6;
  if (tid < 128) {
    int idx = min(m0 + tid, cnt - 1);
    stok[tid] = rtok[e * T_TOK + idx];
    scoef[tid] = rw[e * T_TOK + idx];
  }
  int c0id = wv * 128 + lane, c1id = c0id + 64;
  int rA0 = c0id >> 2, rA1 = c1id >> 2;
  int kq0 = (c0id & 3) * 8, kq1 = (c1id & 3) * 8;
  int hrow0 = blockIdx.x * 128;
  const ushort* he = h + (size_t)e * MC * ID;
  const ushort* aSrc0 = he + (size_t)(hrow0 + rA0) * ID + kq0;
  const ushort* aSrc1 = he + (size_t)(hrow0 + rA1) * ID + kq1;
  const ushort* bBase = w2t + ((size_t)e * HD + n0) * ID;
  const ushort* bSrc0 = bBase + (size_t)rA0 * ID + kq0;
  const ushort* bSrc1 = bBase + (size_t)rA1 * ID + kq1;
  ushort* aDst = As + (size_t)wv * 128 * 8;
  ushort* bDst = Bs + (size_t)wv * 128 * 8;
  f32x4 acc[4][4] = {};
  int lr = lane & 15, lk = lane >> 4;
  int wr = wv >> 1, wc = wv & 1;
  const ushort* aRd = As + ((wr * 64 + lr) * 32 + lk * 8);
  const ushort* bRd = Bs + ((wc * 64 + lr) * 32 + lk * 8);
  for (int k0 = 0; k0 < ID; k0 += 32) {
    gload16(aSrc0 + k0, aDst);
    gload16(aSrc1 + k0, aDst + 64 * 8);
    gload16(bSrc0 + k0, bDst);
    gload16(bSrc1 + k0, bDst + 64 * 8);
    __syncthreads();
    bf16x8 af[4], bfr[4];
#pragma unroll
    for (int i = 0; i < 4; ++i) {
      af[i] = *(const bf16x8*)(aRd + i * 16 * 32);
      bfr[i] = *(const bf16x8*)(bRd + i * 16 * 32);
    }
#pragma unroll
    for (int mi = 0; mi < 4; ++mi)
#pragma unroll
      for (int ni = 0; ni < 4; ++ni)
        acc[mi][ni] = __builtin_amdgcn_mfma_f32_16x16x32_bf16(af[mi], bfr[ni], acc[mi][ni], 0, 0, 0);
    __syncthreads();
  }
#pragma unroll
  for (int ni = 0; ni < 4; ++ni) {
    int ng = n0 + wc * 64 + ni * 16 + lr;  // < 512
    float b2v = b2[e * HD + ng];
#pragma unroll
    for (int mi = 0; mi < 4; ++mi) {
      int rloc = wr * 64 + mi * 16 + lk * 4;
#pragma unroll
      for (int r = 0; r < 4; ++r) {
        int m_l = rloc + r;
        if (m0 + m_l < cnt) {
          float v = (acc[mi][ni][r] + b2v) * scoef[m_l];
          unsafeAtomicAdd(&out[(size_t)stok[m_l] * HD + ng], v);
        }
      }
    }
  }
}

// ---------------- host ----------------
extern "C" void kernel_launch(void* const* d_in, const int* in_sizes, int n_in,
                              void* d_out, int out_size, void* d_ws, size_t ws_size,
                              hipStream_t stream) {
  const float* x  = (const float*)d_in[0];
  const float* gw = (const float*)d_in[1];
  const float* gb = (const float*)d_in[2];
  const float* w1 = (const float*)d_in[3];
  const float* b1 = (const float*)d_in[4];
  const float* w2 = (const float*)d_in[5];
  const float* b2 = (const float*)d_in[6];
  float* out = (float*)d_out;

  char* p = (char*)d_ws;
  ushort* xb   = (ushort*)p; p += (size_t)T_TOK * HD * 2;   // 33.5 MB
  ushort* w1t  = (ushort*)p; p += (size_t)NE * ID * HD * 2; // 16.8 MB
  ushort* w2t  = (ushort*)p; p += (size_t)NE * HD * ID * 2; // 16.8 MB
  int*    rtok = (int*)p;    p += (size_t)NE * T_TOK * 4;   // 1 MB
  float*  rw   = (float*)p;  p += (size_t)NE * T_TOK * 4;   // 1 MB
  uchar2* tope = (uchar2*)p; p += (size_t)T_TOK * 2;
  float2* tw   = (float2*)p; p += (size_t)T_TOK * 8;
  int*  counts = (int*)p;    p += 128;
  ushort* hbuf = (ushort*)p;
  size_t fixed = (size_t)(p - (char*)d_ws);
  size_t avail = ws_size > fixed ? ws_size - fixed : 0;

  // h capacity per expert (chunk-local rows), ws_size-dependent (constant per session)
  int MC = 256;
  for (int cand = 8192; cand >= 256; cand >>= 1) {
    if ((size_t)NE * cand * ID * 2 <= avail) { MC = cand; break; }
  }
  int nchunk = (T_TOK + MC - 1) / MC;
  int MCB = MC / 128 > 0 ? MC / 128 : 1;

  k_zero<<<2048, 256, 0, stream>>>((float4*)out, T_TOK * HD / 4, counts);
  k_cast_gate<<<T_TOK / 4, 256, 0, stream>>>(x, gw, gb, xb, tope, tw);
  k_route<<<T_TOK / 256, 256, 0, stream>>>(tope, tw, rtok, rw, counts);
  // w1: [E][512][2048] -> w1t [E][2048][512]
  k_transpose<<<dim3(ID / 32, HD / 32, NE), dim3(32, 8), 0, stream>>>(w1, w1t, HD, ID);
  // w2: [E][2048][512] -> w2t [E][512][2048]
  k_transpose<<<dim3(HD / 32, ID / 32, NE), dim3(32, 8), 0, stream>>>(w2, w2t, ID, HD);

  for (int c = 0; c < nchunk; ++c) {
    k_ffn1<<<dim3(MCB, ID / 128, NE), 256, 0, stream>>>(xb, w1t, b1, rtok, counts,
                                                        hbuf, c * MC, MC);
    k_ffn2<<<dim3(MCB, HD / 128, NE), 256, 0, stream>>>(hbuf, w2t, b2, rtok, rw, counts,
                                                        out, c * MC, MC);
  }
}